// Round 1
// baseline (19.117 us; speedup 1.0000x reference)
//
#include <hip/hip_runtime.h>

#define BATCH 2048
#define NSPIN 2
#define NPS 8
#define DFEAT 256
#define NION 4
#define DSP 3

// Block: 256 threads handles 8 walkers x 1 spin.
// Wave q (0..3) owns f-quarter q of the length-256 dot products.
// Lane (0..63) -> (walker 0..7, electron i 0..7); 16 accumulators per lane
// (8 k's of A-half + 8 k's of Bt-half).
__global__ __launch_bounds__(256) void ppdet_kernel(
    const float* __restrict__ eq,      // (B, 16, 256)
    const float* __restrict__ r_ei,    // (B, 16, 4, 3)
    const float* __restrict__ W,       // (2, 512, 8)
    const float* __restrict__ bias,    // (2, 8)
    const float* __restrict__ env_dim, // (2, 8, 4, 3, 3)
    const float* __restrict__ env_ion, // (2, 4, 8)
    float* __restrict__ out)           // (2, 2048, 8) flat: s-major
{
    __shared__ float part[4 * 64 * 16]; // quarter partial sums
    __shared__ float AB[64 * 16];       // [row=(w*8+i)][k<8:A(+bias), k>=8:Bt]
    __shared__ float envl[8 * 8 * 8];   // [w][j][k]

    const int tid = threadIdx.x;
    const int bid = blockIdx.x;
    const int s  = bid & 1;
    const int b0 = (bid >> 1) * 8;

    const int q    = __builtin_amdgcn_readfirstlane(tid >> 6); // wave-uniform
    const int lane = tid & 63;
    const int wl   = lane >> 3; // walker 0..7
    const int ii   = lane & 7;  // electron row i

    const float* Ws   = W + (size_t)s * (2 * DFEAT * NPS); // 4096 floats
    const float* xrow = eq + ((size_t)(b0 + wl) * (NSPIN * NPS) + s * NPS + ii) * DFEAT
                        + q * 64;

    float acc[16];
#pragma unroll
    for (int k = 0; k < 16; ++k) acc[k] = 0.f;

#pragma unroll 4
    for (int f4 = 0; f4 < 16; ++f4) {
        const float4 xv = ((const float4*)xrow)[f4];
#pragma unroll
        for (int c = 0; c < 4; ++c) {
            const float xc = (c == 0) ? xv.x : (c == 1) ? xv.y : (c == 2) ? xv.z : xv.w;
            // uniform addresses -> scalar loads (q, f4, c, s all uniform)
            const float* w1 = Ws + (size_t)(q * 64 + f4 * 4 + c) * NPS;
            const float* w2 = w1 + DFEAT * NPS; // second half of the 512 rows
#pragma unroll
            for (int k = 0; k < 8; ++k) acc[k] += xc * w1[k];
#pragma unroll
            for (int k = 0; k < 8; ++k) acc[8 + k] += xc * w2[k];
        }
    }

#pragma unroll
    for (int k = 0; k < 16; ++k) part[(q * 64 + lane) * 16 + k] = acc[k];

    __syncthreads();

    // Reduce the 4 quarter-partials; fold bias into the A half.
#pragma unroll
    for (int t = 0; t < 4; ++t) {
        int idx = t * 256 + tid;           // 0..1023 = 64 rows x 16 k
        int row = idx >> 4, k = idx & 15;
        float v = part[(0 * 64 + row) * 16 + k] + part[(1 * 64 + row) * 16 + k]
                + part[(2 * 64 + row) * 16 + k] + part[(3 * 64 + row) * 16 + k];
        if (k < 8) v += bias[s * NPS + k];
        AB[row * 16 + k] = v;
    }

    // Envelope: env[w,j,k] = sum_a env_ion[s,a,k] * exp(-||r[b,s,j,a,:] @ env_dim[s,k,a]||)
#pragma unroll
    for (int t = 0; t < 2; ++t) {
        int task = t * 256 + tid;          // 0..511 = (w,j,k)
        int w = task >> 6, j = (task >> 3) & 7, k = task & 7;
        float e = 0.f;
#pragma unroll
        for (int a = 0; a < NION; ++a) {
            const float* rr = r_ei
                + (((size_t)(b0 + w) * (NSPIN * NPS) + s * NPS + j) * NION + a) * DSP;
            float r0 = rr[0], r1 = rr[1], r2 = rr[2];
            const float* Md = env_dim + (((size_t)s * NPS + k) * NION + a) * 9;
            float e0 = r0 * Md[0] + r1 * Md[3] + r2 * Md[6];
            float e1 = r0 * Md[1] + r1 * Md[4] + r2 * Md[7];
            float e2 = r0 * Md[2] + r1 * Md[5] + r2 * Md[8];
            float dist = sqrtf(e0 * e0 + e1 * e1 + e2 * e2);
            e += env_ion[((size_t)s * NION + a) * NPS + k] * __expf(-dist);
        }
        envl[task] = e;
    }

    __syncthreads();

    // One 8x8 determinant per thread (64 dets per block).
    if (tid < 64) {
        int w = tid >> 3, i = tid & 7;
        float Arow[8];
#pragma unroll
        for (int k = 0; k < 8; ++k) Arow[k] = AB[(w * 8 + i) * 16 + k];
        float M[8][8];
#pragma unroll
        for (int j = 0; j < 8; ++j) {
#pragma unroll
            for (int k = 0; k < 8; ++k)
                M[j][k] = (Arow[k] + AB[(w * 8 + j) * 16 + 8 + k]) * envl[(w * 8 + j) * 8 + k];
        }
        // LU with partial pivoting; all register indices compile-time (rule #20).
        float det = 1.f;
#pragma unroll
        for (int p = 0; p < 8; ++p) {
            int piv = p;
            float mx = fabsf(M[p][p]);
#pragma unroll
            for (int r2 = p + 1; r2 < 8; ++r2) {
                float v = fabsf(M[r2][p]);
                if (v > mx) { mx = v; piv = r2; }
            }
#pragma unroll
            for (int r2 = p + 1; r2 < 8; ++r2) {
                bool sw = (piv == r2);
#pragma unroll
                for (int c = p; c < 8; ++c) {
                    float a = M[p][c], bb = M[r2][c];
                    M[p][c]  = sw ? bb : a;
                    M[r2][c] = sw ? a : bb;
                }
            }
            det = (piv != p) ? -det : det;
            float d = M[p][p];
            det *= d;
            float inv = (d != 0.f) ? 1.f / d : 0.f;
#pragma unroll
            for (int r2 = p + 1; r2 < 8; ++r2) {
                float fct = M[r2][p] * inv;
#pragma unroll
                for (int c = p + 1; c < 8; ++c) M[r2][c] -= fct * M[p][c];
            }
        }
        out[(size_t)s * (BATCH * NPS) + (size_t)(b0 + w) * NPS + i] = det;
    }
}

extern "C" void kernel_launch(void* const* d_in, const int* in_sizes, int n_in,
                              void* d_out, int out_size, void* d_ws, size_t ws_size,
                              hipStream_t stream) {
    const float* eq      = (const float*)d_in[0];
    const float* r_ei    = (const float*)d_in[1];
    const float* W       = (const float*)d_in[2];
    const float* bias    = (const float*)d_in[3];
    const float* env_dim = (const float*)d_in[4];
    const float* env_ion = (const float*)d_in[5];
    float* out = (float*)d_out;

    const int grid = (BATCH / 8) * NSPIN; // 512 blocks
    ppdet_kernel<<<grid, 256, 0, stream>>>(eq, r_ei, W, bias, env_dim, env_ion, out);
}

// Round 2
// 17.211 us; speedup vs baseline: 1.1107x; 1.1107x over previous
//
#include <hip/hip_runtime.h>

#define BATCH 2048
#define NPS 8
#define DFEAT 256

// Block: 512 threads = 8 waves, handles 8 walkers x 1 spin (64 x-rows, 64 dets).
// Wave wq owns the wave-uniform f-chunk [wq*32, wq*32+32) -> W reads scalarize.
// Lane (0..63) = one x-row (walker wl, electron ii); 16 accumulators
// (8 k of A = x_i . W1, 8 k of Bt = x_j . W2).
__global__ __launch_bounds__(512) void ppdet_kernel(
    const float* __restrict__ eq,      // (B, 16, 256)
    const float* __restrict__ r_ei,    // (B, 16, 4, 3)
    const float* __restrict__ W,       // (2, 512, 8)
    const float* __restrict__ bias,    // (2, 8)
    const float* __restrict__ env_dim, // (2, 8, 4, 3, 3)
    const float* __restrict__ env_ion, // (2, 4, 8)
    float* __restrict__ out)           // (2, 2048, 8)
{
    __shared__ __align__(16) float part[8 * 64 * 16]; // 32 KB, XOR-swizzled slots
    __shared__ __align__(16) float AB[64 * 16];       // [row][k<8:A+bias, k>=8:Bt]
    __shared__ __align__(16) float envl[512];         // [w][j][k]

    const int tid = threadIdx.x;
    const int bid = blockIdx.x;
    const int s  = bid & 1;
    const int b0 = (bid >> 1) * 8;

    const int wq   = __builtin_amdgcn_readfirstlane(tid >> 6); // 0..7, wave-uniform
    const int lane = tid & 63;
    const int wl   = lane >> 3, ii = lane & 7;

    const float* wb1 = W + s * 4096 + wq * (32 * NPS); // this wave's 32 W1 rows
    const size_t grow = (size_t)(b0 + wl) * 16 + s * 8 + ii;
    const float* xrow = eq + grow * DFEAT + wq * 32;

    float4 xv[8];
#pragma unroll
    for (int u = 0; u < 8; ++u) xv[u] = ((const float4*)xrow)[u];

    float acc[16];
#pragma unroll
    for (int k = 0; k < 16; ++k) acc[k] = 0.f;

#pragma unroll
    for (int u = 0; u < 8; ++u) {
        const float* wr = wb1 + u * 32;
        float xs0 = xv[u].x, xs1 = xv[u].y, xs2 = xv[u].z, xs3 = xv[u].w;
#pragma unroll
        for (int c = 0; c < 4; ++c) {
            float xc = (c == 0) ? xs0 : (c == 1) ? xs1 : (c == 2) ? xs2 : xs3;
#pragma unroll
            for (int k = 0; k < 8; ++k) {
                acc[k]     = fmaf(xc, wr[c * 8 + k],        acc[k]);
                acc[8 + k] = fmaf(xc, wr[2048 + c * 8 + k], acc[8 + k]);
            }
        }
    }

    // Store partials; swizzle the 4-float slot so b128 writes hit the 8-way floor.
    {
        float* pb = part + (wq * 64 + lane) * 16;
        const int sw = (lane >> 1) & 3;
#pragma unroll
        for (int kg = 0; kg < 4; ++kg) {
            int slot = kg ^ sw;
            float4 v = make_float4(acc[kg * 4], acc[kg * 4 + 1],
                                   acc[kg * 4 + 2], acc[kg * 4 + 3]);
            *(float4*)(pb + slot * 4) = v;
        }
    }

    // Envelope: task = (w, k, j) with j fastest so 8 lanes share (k,a) tables.
    {
        const int w = tid >> 6, k = (tid >> 3) & 7, j = tid & 7;
        const size_t rrow = ((size_t)(b0 + w) * 16 + s * 8 + j) * 12;
        const float4* rp = (const float4*)(r_ei + rrow);
        float4 ra = rp[0], rb = rp[1], rc = rp[2];
        float rr[12] = {ra.x, ra.y, ra.z, ra.w, rb.x, rb.y, rb.z, rb.w,
                        rc.x, rc.y, rc.z, rc.w};
        float e = 0.f;
#pragma unroll
        for (int a = 0; a < 4; ++a) {
            const float* Md = env_dim + ((size_t)(s * 8 + k) * 4 + a) * 9;
            float r0 = rr[a * 3], r1 = rr[a * 3 + 1], r2 = rr[a * 3 + 2];
            float e0 = r0 * Md[0] + r1 * Md[3] + r2 * Md[6];
            float e1 = r0 * Md[1] + r1 * Md[4] + r2 * Md[7];
            float e2 = r0 * Md[2] + r1 * Md[5] + r2 * Md[8];
            float dist = sqrtf(e0 * e0 + e1 * e1 + e2 * e2);
            e = fmaf(env_ion[(s * 4 + a) * 8 + k], __expf(-dist), e);
        }
        envl[w * 64 + j * 8 + k] = e;
    }

    __syncthreads();

    // Reduce 8 f-chunk partials -> AB (swizzle-aware), fold bias into A half.
    if (tid < 256) {
        const int row = tid >> 2, sl = tid & 3;
        const int g = sl ^ ((row >> 1) & 3); // true k-group held in slot sl
        float4 sum = make_float4(0.f, 0.f, 0.f, 0.f);
#pragma unroll
        for (int q2 = 0; q2 < 8; ++q2) {
            float4 v = *(const float4*)(part + (q2 * 64 + row) * 16 + sl * 4);
            sum.x += v.x; sum.y += v.y; sum.z += v.z; sum.w += v.w;
        }
        if (g < 2) {
            sum.x += bias[s * 8 + g * 4];
            sum.y += bias[s * 8 + g * 4 + 1];
            sum.z += bias[s * 8 + g * 4 + 2];
            sum.w += bias[s * 8 + g * 4 + 3];
        }
        *(float4*)(AB + row * 16 + g * 4) = sum;
    }

    __syncthreads();

    // Cooperative LU: 8 lanes per determinant, lane = row j. No physical swaps;
    // max-pivot per step, sign from pivot-sequence parity.
    {
        const int grp = tid >> 3;
        const int w = grp >> 3, i = grp & 7, j = tid & 7;
        const float* Arow = AB + (w * 8 + i) * 16;
        const float* Brow = AB + (w * 8 + j) * 16 + 8;
        const float* Erow = envl + w * 64 + j * 8;
        float m[8];
#pragma unroll
        for (int k = 0; k < 8; ++k) m[k] = (Arow[k] + Brow[k]) * Erow[k];

        float det_acc = 1.f;
        bool elim = false;
        int pis[8];
#pragma unroll
        for (int p = 0; p < 8; ++p) {
            float aval = elim ? -1.f : fabsf(m[p]);
            int aidx = j;
#pragma unroll
            for (int mb = 1; mb < 8; mb <<= 1) {
                float ov = __shfl_xor(aval, mb);
                int   oi = __shfl_xor(aidx, mb);
                bool take = (ov > aval) || (ov == aval && oi < aidx);
                aval = take ? ov : aval;
                aidx = take ? oi : aidx;
            }
            pis[p] = aidx;                    // pivot row (group-uniform)
            const int src = (tid & 56) | aidx;
            float prow[8];
#pragma unroll
            for (int k = 0; k < 8; ++k) prow[k] = __shfl(m[k], src);
            det_acc *= prow[p];
            elim = elim || (j == aidx);
            float f = (!elim && aval > 0.f)
                        ? m[p] * __builtin_amdgcn_rcpf(prow[p]) : 0.f;
#pragma unroll
            for (int k = 0; k < 8; ++k) m[k] = fmaf(-f, prow[k], m[k]);
        }
        int inv = 0;
#pragma unroll
        for (int a = 0; a < 8; ++a)
#pragma unroll
            for (int b2 = a + 1; b2 < 8; ++b2) inv += (pis[a] > pis[b2]) ? 1 : 0;
        if (j == 0) {
            float dd = (inv & 1) ? -det_acc : det_acc;
            out[(size_t)s * (BATCH * NPS) + (size_t)(b0 + w) * NPS + i] = dd;
        }
    }
}

extern "C" void kernel_launch(void* const* d_in, const int* in_sizes, int n_in,
                              void* d_out, int out_size, void* d_ws, size_t ws_size,
                              hipStream_t stream) {
    const float* eq      = (const float*)d_in[0];
    const float* r_ei    = (const float*)d_in[1];
    const float* W       = (const float*)d_in[2];
    const float* bias    = (const float*)d_in[3];
    const float* env_dim = (const float*)d_in[4];
    const float* env_ion = (const float*)d_in[5];
    float* out = (float*)d_out;

    ppdet_kernel<<<512, 512, 0, stream>>>(eq, r_ei, W, bias, env_dim, env_ion, out);
}

// Round 3
// 16.933 us; speedup vs baseline: 1.1290x; 1.0165x over previous
//
#include <hip/hip_runtime.h>

#define BATCH 2048
#define NPS 8
#define DFEAT 256

// Block: 512 threads = 8 waves, handles 8 walkers x 1 spin (64 rows, 64 dets).
// Phase 0: wave wq stages walker wq's 8 eq-rows into LDS, TRANSPOSED+swizzled,
//          with perfectly coalesced 1KB global loads (one row per instruction).
// Phase 1: wave wq computes the f-chunk [wq*32,wq*32+32) partial dots for all
//          64 rows (lane = row), W via wave-uniform (scalar) loads.
// Phase 2: reduce 8 chunk-partials -> AB, envelope, cooperative 8-lane LU.
__global__ __launch_bounds__(512) void ppdet_kernel(
    const float* __restrict__ eq,      // (B, 16, 256)
    const float* __restrict__ r_ei,    // (B, 16, 4, 3)
    const float* __restrict__ W,       // (2, 512, 8)
    const float* __restrict__ bias,    // (2, 8)
    const float* __restrict__ env_dim, // (2, 8, 4, 3, 3)
    const float* __restrict__ env_ion, // (2, 4, 8)
    float* __restrict__ out)           // (2, 2048, 8)
{
    // XT: 256 x 64 transposed x-tile (64KB). After sync2 its space is reused
    // as part[8*64*16] (32KB). AB/envl live above it.
    __shared__ __align__(16) float smem[16384 + 1024 + 512];
    float* XT   = smem;
    float* part = smem;
    float* AB   = smem + 16384;
    float* envl = smem + 16384 + 1024;

    const int tid = threadIdx.x;
    const int bid = blockIdx.x;
    const int s  = bid & 1;
    const int b0 = (bid >> 1) * 8;

    const int wq   = __builtin_amdgcn_readfirstlane(tid >> 6); // 0..7 uniform
    const int lane = tid & 63;

    // ---- Phase 0a: coalesced stage, transposed write XT[f][r ^ ((f>>2)&31)]
    {
        const float* gbase = eq + ((size_t)(b0 + wq) * 16 + s * 8) * DFEAT;
        const int msk = lane & 31; // == (f>>2)&31 with f = lane*4+c
#pragma unroll
        for (int ii = 0; ii < 8; ++ii) {
            float4 v = ((const float4*)(gbase + ii * DFEAT))[lane];
            const int r = wq * 8 + ii;
            float* dst = XT + (size_t)(lane * 4) * 64 + (r ^ msk);
            dst[0] = v.x; dst[64] = v.y; dst[128] = v.z; dst[192] = v.w;
        }
    }

    // ---- Phase 0b: envelope (independent; overlaps staging latency)
    {
        const int w = tid >> 6, k = (tid >> 3) & 7, j = tid & 7;
        const size_t rrow = ((size_t)(b0 + w) * 16 + s * 8 + j) * 12;
        const float4* rp = (const float4*)(r_ei + rrow);
        float4 ra = rp[0], rb = rp[1], rc = rp[2];
        float rr[12] = {ra.x, ra.y, ra.z, ra.w, rb.x, rb.y, rb.z, rb.w,
                        rc.x, rc.y, rc.z, rc.w};
        float e = 0.f;
#pragma unroll
        for (int a = 0; a < 4; ++a) {
            const float* Md = env_dim + ((size_t)(s * 8 + k) * 4 + a) * 9;
            float r0 = rr[a * 3], r1 = rr[a * 3 + 1], r2 = rr[a * 3 + 2];
            float e0 = r0 * Md[0] + r1 * Md[3] + r2 * Md[6];
            float e1 = r0 * Md[1] + r1 * Md[4] + r2 * Md[7];
            float e2 = r0 * Md[2] + r1 * Md[5] + r2 * Md[8];
            float dist = sqrtf(e0 * e0 + e1 * e1 + e2 * e2);
            e = fmaf(env_ion[(s * 4 + a) * 8 + k], __expf(-dist), e);
        }
        envl[w * 64 + j * 8 + k] = e;
    }

    __syncthreads(); // XT staged

    // ---- Phase 1: GEMM partials from LDS; W via uniform scalar loads
    float acc[16];
#pragma unroll
    for (int k = 0; k < 16; ++k) acc[k] = 0.f;

    const float* wb1 = W + s * 4096 + wq * 256;
#pragma unroll
    for (int g8 = 0; g8 < 8; ++g8) {
        const int g = wq * 8 + g8;
        const float* xb = XT + (size_t)(4 * g) * 64 + (lane ^ (g & 31));
        float xs0 = xb[0], xs1 = xb[64], xs2 = xb[128], xs3 = xb[192];
        const float* wr = wb1 + g8 * 32;
#pragma unroll
        for (int c = 0; c < 4; ++c) {
            float xc = (c == 0) ? xs0 : (c == 1) ? xs1 : (c == 2) ? xs2 : xs3;
#pragma unroll
            for (int k = 0; k < 8; ++k) {
                acc[k]     = fmaf(xc, wr[c * 8 + k],        acc[k]);
                acc[8 + k] = fmaf(xc, wr[2048 + c * 8 + k], acc[8 + k]);
            }
        }
    }

    __syncthreads(); // all XT reads done -> safe to alias part over XT

    // ---- Phase 2a: store partials (swizzled slots, b128 at the 8-way floor)
    {
        float* pb = part + (wq * 64 + lane) * 16;
        const int sw = (lane >> 1) & 3;
#pragma unroll
        for (int kg = 0; kg < 4; ++kg) {
            int slot = kg ^ sw;
            float4 v = make_float4(acc[kg * 4], acc[kg * 4 + 1],
                                   acc[kg * 4 + 2], acc[kg * 4 + 3]);
            *(float4*)(pb + slot * 4) = v;
        }
    }

    __syncthreads();

    // ---- Phase 2b: reduce 8 chunk-partials -> AB, fold bias into A half
    if (tid < 256) {
        const int row = tid >> 2, sl = tid & 3;
        const int g = sl ^ ((row >> 1) & 3);
        float4 sum = make_float4(0.f, 0.f, 0.f, 0.f);
#pragma unroll
        for (int q2 = 0; q2 < 8; ++q2) {
            float4 v = *(const float4*)(part + (q2 * 64 + row) * 16 + sl * 4);
            sum.x += v.x; sum.y += v.y; sum.z += v.z; sum.w += v.w;
        }
        if (g < 2) {
            sum.x += bias[s * 8 + g * 4];
            sum.y += bias[s * 8 + g * 4 + 1];
            sum.z += bias[s * 8 + g * 4 + 2];
            sum.w += bias[s * 8 + g * 4 + 3];
        }
        *(float4*)(AB + row * 16 + g * 4) = sum;
    }

    __syncthreads();

    // ---- Phase 2c: cooperative LU, 8 lanes per determinant (lane = row j)
    {
        const int grp = tid >> 3;
        const int w = grp >> 3, i = grp & 7, j = tid & 7;
        const float* Arow = AB + (w * 8 + i) * 16;
        const float* Brow = AB + (w * 8 + j) * 16 + 8;
        const float* Erow = envl + w * 64 + j * 8;
        float m[8];
#pragma unroll
        for (int k = 0; k < 8; ++k) m[k] = (Arow[k] + Brow[k]) * Erow[k];

        float det_acc = 1.f;
        bool elim = false;
        int pis[8];
#pragma unroll
        for (int p = 0; p < 8; ++p) {
            float aval = elim ? -1.f : fabsf(m[p]);
            int aidx = j;
#pragma unroll
            for (int mb = 1; mb < 8; mb <<= 1) {
                float ov = __shfl_xor(aval, mb);
                int   oi = __shfl_xor(aidx, mb);
                bool take = (ov > aval) || (ov == aval && oi < aidx);
                aval = take ? ov : aval;
                aidx = take ? oi : aidx;
            }
            pis[p] = aidx;
            const int src = (tid & 56) | aidx;
            float prow[8];
#pragma unroll
            for (int k = 0; k < 8; ++k) prow[k] = __shfl(m[k], src);
            det_acc *= prow[p];
            elim = elim || (j == aidx);
            float f = (!elim && aval > 0.f)
                        ? m[p] * __builtin_amdgcn_rcpf(prow[p]) : 0.f;
#pragma unroll
            for (int k = 0; k < 8; ++k) m[k] = fmaf(-f, prow[k], m[k]);
        }
        int inv = 0;
#pragma unroll
        for (int a = 0; a < 8; ++a)
#pragma unroll
            for (int b2 = a + 1; b2 < 8; ++b2) inv += (pis[a] > pis[b2]) ? 1 : 0;
        if (j == 0) {
            float dd = (inv & 1) ? -det_acc : det_acc;
            out[(size_t)s * (BATCH * NPS) + (size_t)(b0 + w) * NPS + i] = dd;
        }
    }
}

extern "C" void kernel_launch(void* const* d_in, const int* in_sizes, int n_in,
                              void* d_out, int out_size, void* d_ws, size_t ws_size,
                              hipStream_t stream) {
    const float* eq      = (const float*)d_in[0];
    const float* r_ei    = (const float*)d_in[1];
    const float* W       = (const float*)d_in[2];
    const float* bias    = (const float*)d_in[3];
    const float* env_dim = (const float*)d_in[4];
    const float* env_ion = (const float*)d_in[5];
    float* out = (float*)d_out;

    ppdet_kernel<<<512, 512, 0, stream>>>(eq, r_ei, W, bias, env_dim, env_ion, out);
}

// Round 4
// 16.135 us; speedup vs baseline: 1.1848x; 1.0494x over previous
//
#include <hip/hip_runtime.h>

#define BATCH 2048
#define NPS 8
#define DFEAT 256

// Block: 512 threads = 8 waves, handles 8 walkers x 1 spin (64 rows, 64 dets).
// Wave wq owns f-chunk [wq*32, wq*32+32) -> W reads are wave-uniform (scalar).
// Lane (0..63) = one x-row; 16 accumulators (8 k of A = x_i.W1, 8 k of Bt = x_j.W2).
// Det phase: serial in-register LU per thread (tid<64) -- no cross-lane DS ops.
__global__ __launch_bounds__(512) void ppdet_kernel(
    const float* __restrict__ eq,      // (B, 16, 256)
    const float* __restrict__ r_ei,    // (B, 16, 4, 3)
    const float* __restrict__ W,       // (2, 512, 8)
    const float* __restrict__ bias,    // (2, 8)
    const float* __restrict__ env_dim, // (2, 8, 4, 3, 3)
    const float* __restrict__ env_ion, // (2, 4, 8)
    float* __restrict__ out)           // (2, 2048, 8)
{
    __shared__ __align__(16) float part[8 * 64 * 16]; // 32 KB, XOR-swizzled slots
    __shared__ __align__(16) float AB[64 * 16];       // [row][k<8:A+bias, k>=8:Bt]
    __shared__ __align__(16) float envl[512];         // [w][j][k]

    const int tid = threadIdx.x;
    const int bid = blockIdx.x;
    const int s  = bid & 1;
    const int b0 = (bid >> 1) * 8;

    const int wq   = __builtin_amdgcn_readfirstlane(tid >> 6); // 0..7, uniform
    const int lane = tid & 63;
    const int wl   = lane >> 3, ii = lane & 7;

    const float* wb1 = W + s * 4096 + wq * 256; // this wave's 32 W1 rows
    const size_t grow = (size_t)(b0 + wl) * 16 + s * 8 + ii;
    const float* xrow = eq + grow * DFEAT + wq * 32;

    float4 xv[8];
#pragma unroll
    for (int u = 0; u < 8; ++u) xv[u] = ((const float4*)xrow)[u];

    float acc[16];
#pragma unroll
    for (int k = 0; k < 16; ++k) acc[k] = 0.f;

#pragma unroll
    for (int u = 0; u < 8; ++u) {
        const float* wr = wb1 + u * 32;
        float xs0 = xv[u].x, xs1 = xv[u].y, xs2 = xv[u].z, xs3 = xv[u].w;
#pragma unroll
        for (int c = 0; c < 4; ++c) {
            float xc = (c == 0) ? xs0 : (c == 1) ? xs1 : (c == 2) ? xs2 : xs3;
#pragma unroll
            for (int k = 0; k < 8; ++k) {
                acc[k]     = fmaf(xc, wr[c * 8 + k],        acc[k]);
                acc[8 + k] = fmaf(xc, wr[2048 + c * 8 + k], acc[8 + k]);
            }
        }
    }

    // Store partials; swizzled 4-float slot keeps b128 writes at the 8-way floor.
    {
        float* pb = part + (wq * 64 + lane) * 16;
        const int sw = (lane >> 1) & 3;
#pragma unroll
        for (int kg = 0; kg < 4; ++kg) {
            int slot = kg ^ sw;
            float4 v = make_float4(acc[kg * 4], acc[kg * 4 + 1],
                                   acc[kg * 4 + 2], acc[kg * 4 + 3]);
            *(float4*)(pb + slot * 4) = v;
        }
    }

    // Envelope: task = (w, k, j), j fastest so 8 lanes share (k,a) tables.
    {
        const int w = tid >> 6, k = (tid >> 3) & 7, j = tid & 7;
        const size_t rrow = ((size_t)(b0 + w) * 16 + s * 8 + j) * 12;
        const float4* rp = (const float4*)(r_ei + rrow);
        float4 ra = rp[0], rb = rp[1], rc = rp[2];
        float rr[12] = {ra.x, ra.y, ra.z, ra.w, rb.x, rb.y, rb.z, rb.w,
                        rc.x, rc.y, rc.z, rc.w};
        float e = 0.f;
#pragma unroll
        for (int a = 0; a < 4; ++a) {
            const float* Md = env_dim + ((size_t)(s * 8 + k) * 4 + a) * 9;
            float r0 = rr[a * 3], r1 = rr[a * 3 + 1], r2 = rr[a * 3 + 2];
            float e0 = r0 * Md[0] + r1 * Md[3] + r2 * Md[6];
            float e1 = r0 * Md[1] + r1 * Md[4] + r2 * Md[7];
            float e2 = r0 * Md[2] + r1 * Md[5] + r2 * Md[8];
            float dist = sqrtf(e0 * e0 + e1 * e1 + e2 * e2);
            e = fmaf(env_ion[(s * 4 + a) * 8 + k], __expf(-dist), e);
        }
        envl[w * 64 + j * 8 + k] = e;
    }

    __syncthreads();

    // Reduce 8 f-chunk partials -> AB (swizzle-aware), fold bias into A half.
    if (tid < 256) {
        const int row = tid >> 2, sl = tid & 3;
        const int g = sl ^ ((row >> 1) & 3); // true k-group held in slot sl
        float4 sum = make_float4(0.f, 0.f, 0.f, 0.f);
#pragma unroll
        for (int q2 = 0; q2 < 8; ++q2) {
            float4 v = *(const float4*)(part + (q2 * 64 + row) * 16 + sl * 4);
            sum.x += v.x; sum.y += v.y; sum.z += v.z; sum.w += v.w;
        }
        if (g < 2) {
            sum.x += bias[s * 8 + g * 4];
            sum.y += bias[s * 8 + g * 4 + 1];
            sum.z += bias[s * 8 + g * 4 + 2];
            sum.w += bias[s * 8 + g * 4 + 3];
        }
        *(float4*)(AB + row * 16 + g * 4) = sum;
    }

    __syncthreads();

    // One 8x8 determinant per thread (64 dets/block), in-register LU with
    // partial pivoting; all register indices compile-time constants.
    if (tid < 64) {
        const int w = tid >> 3, i = tid & 7;
        float Arow[8];
#pragma unroll
        for (int k = 0; k < 8; ++k) Arow[k] = AB[(w * 8 + i) * 16 + k];
        float M[8][8];
#pragma unroll
        for (int j = 0; j < 8; ++j) {
#pragma unroll
            for (int k = 0; k < 8; ++k)
                M[j][k] = (Arow[k] + AB[(w * 8 + j) * 16 + 8 + k])
                          * envl[w * 64 + j * 8 + k];
        }
        float det = 1.f;
#pragma unroll
        for (int p = 0; p < 8; ++p) {
            int piv = p;
            float mx = fabsf(M[p][p]);
#pragma unroll
            for (int r2 = p + 1; r2 < 8; ++r2) {
                float v = fabsf(M[r2][p]);
                if (v > mx) { mx = v; piv = r2; }
            }
#pragma unroll
            for (int r2 = p + 1; r2 < 8; ++r2) {
                bool sw = (piv == r2);
#pragma unroll
                for (int c = p; c < 8; ++c) {
                    float a = M[p][c], bb = M[r2][c];
                    M[p][c]  = sw ? bb : a;
                    M[r2][c] = sw ? a : bb;
                }
            }
            det = (piv != p) ? -det : det;
            float d = M[p][p];
            det *= d;
            float inv = (d != 0.f) ? 1.f / d : 0.f;
#pragma unroll
            for (int r2 = p + 1; r2 < 8; ++r2) {
                float fct = M[r2][p] * inv;
#pragma unroll
                for (int c = p + 1; c < 8; ++c) M[r2][c] -= fct * M[p][c];
            }
        }
        out[(size_t)s * (BATCH * NPS) + (size_t)(b0 + w) * NPS + i] = det;
    }
}

extern "C" void kernel_launch(void* const* d_in, const int* in_sizes, int n_in,
                              void* d_out, int out_size, void* d_ws, size_t ws_size,
                              hipStream_t stream) {
    const float* eq      = (const float*)d_in[0];
    const float* r_ei    = (const float*)d_in[1];
    const float* W       = (const float*)d_in[2];
    const float* bias    = (const float*)d_in[3];
    const float* env_dim = (const float*)d_in[4];
    const float* env_ion = (const float*)d_in[5];
    float* out = (float*)d_out;

    ppdet_kernel<<<512, 512, 0, stream>>>(eq, r_ei, W, bias, env_dim, env_ion, out);
}